// Round 2
// baseline (781.011 us; speedup 1.0000x reference)
//
#include <hip/hip_runtime.h>

// Problem constants
#define B_      32
#define C_      128
#define H_      64
#define W_      64
#define OUT_    128
#define E_      4
#define INTERM_ 256
#define JSZ     147456      // OUT_*C_*3*3
#define PLANE   4096        // H_*W_

// ---------------------------------------------------------------------------
// Kernel 1: adaptive avg pool -> pooled[b][c]  (one block per (b,c) plane)
// ---------------------------------------------------------------------------
__global__ void pool_kernel(const float* __restrict__ x, float* __restrict__ pooled) {
    const int bc = blockIdx.x;                       // 0..4095 = b*128+c
    const float4* plane = (const float4*)(x + (size_t)bc * PLANE);
    float s = 0.f;
#pragma unroll
    for (int i = 0; i < 4; ++i) {                    // 1024 float4 / 256 threads
        float4 v = plane[threadIdx.x + i * 256];
        s += v.x + v.y + v.z + v.w;
    }
#pragma unroll
    for (int off = 32; off > 0; off >>= 1) s += __shfl_down(s, off);
    __shared__ float ls[4];
    const int wave = threadIdx.x >> 6, lane = threadIdx.x & 63;
    if (lane == 0) ls[wave] = s;
    __syncthreads();
    if (threadIdx.x == 0)
        pooled[bc] = (ls[0] + ls[1] + ls[2] + ls[3]) * (1.f / 4096.f);
}

// ---------------------------------------------------------------------------
// Kernel 2: routing[b][e] = avgpool64( sigmoid(pooled @ rw^T + rb) )
// one block per sample b; thread i handles interm-unit i; wave = e-group of 64
// ---------------------------------------------------------------------------
__global__ void routing_kernel(const float* __restrict__ pooled,
                               const float* __restrict__ rw,
                               const float* __restrict__ rb,
                               float* __restrict__ routing) {
    const int b = blockIdx.x;
    __shared__ float ps[C_];
    if (threadIdx.x < C_) ps[threadIdx.x] = pooled[b * C_ + threadIdx.x];
    __syncthreads();
    const int i = threadIdx.x;                       // 0..255
    const float4* w4 = (const float4*)(rw + (size_t)i * C_);
    float z = rb[i];
#pragma unroll 8
    for (int c4 = 0; c4 < 32; ++c4) {
        float4 wv = w4[c4];
        z += wv.x * ps[c4 * 4 + 0] + wv.y * ps[c4 * 4 + 1]
           + wv.z * ps[c4 * 4 + 2] + wv.w * ps[c4 * 4 + 3];
    }
    float s = 1.f / (1.f + expf(-z));
#pragma unroll
    for (int off = 32; off > 0; off >>= 1) s += __shfl_down(s, off);
    if ((threadIdx.x & 63) == 0)
        routing[b * E_ + (threadIdx.x >> 6)] = s * (1.f / 64.f);
}

// ---------------------------------------------------------------------------
// Kernel 3: weight gen + layout transpose.
// wbuf layout: [b][ot(2)][cc(8)][kc=c*9+k (144)][o (64)]  -- so the conv
// kernel's LDS staging is a pure contiguous float4 copy.
// Block per (cc, ot, b). LDS transpose tile t[o][kc] (pad 148).
// ---------------------------------------------------------------------------
__global__ void wgen_kernel(const float* __restrict__ routing,
                            const float* __restrict__ ew,
                            float* __restrict__ wbuf) {
    const int cc = blockIdx.x;   // 0..7   (c chunk of 16)
    const int ot = blockIdx.y;   // 0..1   (o tile of 64)
    const int b  = blockIdx.z;   // 0..31
    __shared__ float t[64][148];

    const float r0 = routing[b * 4 + 0], r1 = routing[b * 4 + 1];
    const float r2 = routing[b * 4 + 2], r3 = routing[b * 4 + 3];
    const float4* e4 = (const float4*)ew;
    const int estride = JSZ >> 2;                    // 36864 float4 per expert

#pragma unroll
    for (int it = 0; it < 9; ++it) {                 // 2304 float4 / 256 thr
        const int f4 = it * 256 + threadIdx.x;
        const int o = f4 / 36, q = f4 % 36;          // 36 float4 per o
        // global float idx: (ot*64+o)*1152 + cc*144 + q*4  (float4 aligned)
        const int gi = (ot * 64 + o) * 288 + cc * 36 + q;
        float4 a = e4[gi];
        float4 bb = e4[gi + estride];
        float4 c = e4[gi + 2 * estride];
        float4 d = e4[gi + 3 * estride];
        float4 v;
        v.x = r0 * a.x + r1 * bb.x + r2 * c.x + r3 * d.x;
        v.y = r0 * a.y + r1 * bb.y + r2 * c.y + r3 * d.y;
        v.z = r0 * a.z + r1 * bb.z + r2 * c.z + r3 * d.z;
        v.w = r0 * a.w + r1 * bb.w + r2 * c.w + r3 * d.w;
        *(float4*)&t[o][q * 4] = v;
    }
    __syncthreads();
    float* outp = wbuf + (size_t)((b * 2 + ot) * 8 + cc) * 9216;
#pragma unroll
    for (int it = 0; it < 36; ++it) {                // 9216 floats / 256 thr
        const int idx = it * 256 + threadIdx.x;
        const int kc = idx >> 6, o = idx & 63;
        outp[idx] = t[o][kc];                        // coalesced store
    }
}

// ---------------------------------------------------------------------------
// Kernel 4: per-sample grouped 3x3 conv.
// Block = (ot, h, b): 64 o-channels x one 64-wide row.
// 256 threads = 16 og x 16 wg; each thread: 4 consecutive o, 4 consecutive w.
// LDS: xs[c16][row3][72] input slab, wsm[144][64] weight chunk (contig copy).
// ---------------------------------------------------------------------------
__global__ void conv_kernel(const float* __restrict__ x,
                            const float* __restrict__ wbuf,
                            float* __restrict__ out) {
    const int ot = blockIdx.x;   // 0..1
    const int h  = blockIdx.y;   // 0..63
    const int b  = blockIdx.z;   // 0..31

    __shared__ float xs[16][3][72];     // 13824 B
    __shared__ float wsm[9216];         // 36864 B   [kc=c*9+k][o64]

    const int tid = threadIdx.x;
    const int og = tid >> 4;            // 0..15 -> o = ot*64 + og*4 + oo
    const int wg = tid & 15;            // 0..15 -> w = wg*4 + p
    const int wbase = wg * 4;

    float acc[4][4];
#pragma unroll
    for (int i = 0; i < 4; ++i)
#pragma unroll
        for (int j = 0; j < 4; ++j) acc[i][j] = 0.f;

    const float* xb = x + (size_t)b * C_ * PLANE;

    for (int cc = 0; cc < 8; ++cc) {
        // ---- stage input slab: 16 c x rows (h-1..h+1) x cols (-1..64) ----
        for (int idx = tid; idx < 16 * 3 * 72; idx += 256) {
            const int c = idx / 216, rem = idx % 216;
            const int r = rem / 72, col = rem % 72;
            const int row = h + r - 1;
            const int xcol = col - 1;
            float v = 0.f;
            if (col < 66 && (unsigned)xcol < 64u && (unsigned)row < 64u)
                v = xb[(size_t)(cc * 16 + c) * PLANE + row * 64 + xcol];
            xs[c][r][col] = v;
        }
        // ---- stage weight chunk: contiguous float4 copy ----
        {
            const float4* src = (const float4*)(wbuf +
                (size_t)((b * 2 + ot) * 8 + cc) * 9216);
            float4* dst = (float4*)wsm;
#pragma unroll
            for (int it = 0; it < 9; ++it)
                dst[it * 256 + tid] = src[it * 256 + tid];
        }
        __syncthreads();

        // ---- compute ----
        for (int c = 0; c < 16; ++c) {
            float xr[3][6];
#pragma unroll
            for (int r = 0; r < 3; ++r) {
                float4 a = *(const float4*)&xs[c][r][wbase];
                float2 e = *(const float2*)&xs[c][r][wbase + 4];
                xr[r][0] = a.x; xr[r][1] = a.y; xr[r][2] = a.z;
                xr[r][3] = a.w; xr[r][4] = e.x; xr[r][5] = e.y;
            }
#pragma unroll
            for (int k = 0; k < 9; ++k) {
                const int kh = k / 3, kw = k % 3;
                float4 wv = *(const float4*)&wsm[(c * 9 + k) * 64 + og * 4];
#pragma unroll
                for (int p = 0; p < 4; ++p) {
                    const float xv = xr[kh][p + kw];
                    acc[0][p] += wv.x * xv;
                    acc[1][p] += wv.y * xv;
                    acc[2][p] += wv.z * xv;
                    acc[3][p] += wv.w * xv;
                }
            }
        }
        __syncthreads();
    }

    // ---- write 4 o-planes x 4 px, float4 stores ----
    float* ob = out + (((size_t)b * OUT_ + ot * 64 + og * 4) * H_ + h) * W_ + wbase;
#pragma unroll
    for (int oo = 0; oo < 4; ++oo) {
        float4 v = { acc[oo][0], acc[oo][1], acc[oo][2], acc[oo][3] };
        *(float4*)(ob + (size_t)oo * PLANE) = v;
    }
}

// ---------------------------------------------------------------------------
extern "C" void kernel_launch(void* const* d_in, const int* in_sizes, int n_in,
                              void* d_out, int out_size, void* d_ws, size_t ws_size,
                              hipStream_t stream) {
    const float* x  = (const float*)d_in[0];   // [32,128,64,64]
    const float* rw = (const float*)d_in[1];   // [256,128]
    const float* rb = (const float*)d_in[2];   // [256]
    const float* ew = (const float*)d_in[3];   // [4,147456]
    float* out = (float*)d_out;                // [32,128,64,64]

    float* pooled  = (float*)d_ws;             // 4096 floats
    float* routing = pooled + 4096;            // 128 floats
    float* wbuf    = pooled + 8192;            // 4718592 floats (18.9 MB)

    pool_kernel<<<dim3(B_ * C_), 256, 0, stream>>>(x, pooled);
    routing_kernel<<<dim3(B_), 256, 0, stream>>>(pooled, rw, rb, routing);
    wgen_kernel<<<dim3(8, 2, B_), 256, 0, stream>>>(routing, ew, wbuf);
    conv_kernel<<<dim3(2, H_, B_), 256, 0, stream>>>(x, wbuf, out);
}

// Round 4
// 189.427 us; speedup vs baseline: 4.1230x; 4.1230x over previous
//
#include <hip/hip_runtime.h>

typedef __attribute__((ext_vector_type(8))) short short8;
typedef __attribute__((ext_vector_type(4))) float f32x4;

#define B_      32
#define C_      128
#define H_      64
#define W_      64
#define OUT_    128
#define PLANE   4096
#define EWSZ    147456      // per-expert weight count

// bf16 round-to-nearest-even
__device__ inline short f2bf(float f) {
    unsigned u = __builtin_bit_cast(unsigned, f);
    u += 0x7fff + ((u >> 16) & 1);
    return (short)(u >> 16);
}

// ---------------------------------------------------------------------------
// Kernel 1: adaptive avg pool -> pooled[b][c]
// ---------------------------------------------------------------------------
__global__ void pool_kernel(const float* __restrict__ x, float* __restrict__ pooled) {
    const int bc = blockIdx.x;
    const float4* plane = (const float4*)(x + (size_t)bc * PLANE);
    float s = 0.f;
#pragma unroll
    for (int i = 0; i < 4; ++i) {
        float4 v = plane[threadIdx.x + i * 256];
        s += v.x + v.y + v.z + v.w;
    }
#pragma unroll
    for (int off = 32; off > 0; off >>= 1) s += __shfl_down(s, off);
    __shared__ float ls[4];
    const int wave = threadIdx.x >> 6, lane = threadIdx.x & 63;
    if (lane == 0) ls[wave] = s;
    __syncthreads();
    if (threadIdx.x == 0)
        pooled[bc] = (ls[0] + ls[1] + ls[2] + ls[3]) * (1.f / 4096.f);
}

// ---------------------------------------------------------------------------
// Kernel 2: routing[b][e]
// ---------------------------------------------------------------------------
__global__ void routing_kernel(const float* __restrict__ pooled,
                               const float* __restrict__ rw,
                               const float* __restrict__ rb,
                               float* __restrict__ routing) {
    const int b = blockIdx.x;
    __shared__ float ps[C_];
    if (threadIdx.x < C_) ps[threadIdx.x] = pooled[b * C_ + threadIdx.x];
    __syncthreads();
    const int i = threadIdx.x;
    const float4* w4 = (const float4*)(rw + (size_t)i * C_);
    float z = rb[i];
#pragma unroll 8
    for (int c4 = 0; c4 < 32; ++c4) {
        float4 wv = w4[c4];
        z += wv.x * ps[c4 * 4 + 0] + wv.y * ps[c4 * 4 + 1]
           + wv.z * ps[c4 * 4 + 2] + wv.w * ps[c4 * 4 + 3];
    }
    float s = 1.f / (1.f + expf(-z));
#pragma unroll
    for (int off = 32; off > 0; off >>= 1) s += __shfl_down(s, off);
    if ((threadIdx.x & 63) == 0)
        routing[b * 4 + (threadIdx.x >> 6)] = s * (1.f / 64.f);
}

// ---------------------------------------------------------------------------
// Kernel 3: weight gen, output = bf16 packed in MFMA A-fragment order.
// wbuf[b][cc(4)] chunk = 36864 bf16, flat idx = ((t*8+mf)*64 + lane)*8 + j
// where element = W_b[o = mf*16 + (lane&15)][c = cc*32 + (lane>>4)*8 + j],
// tap t = kh*3+kw.  grid (cc*9+t = 36, b = 32), 512 threads (mf = tid>>6).
// ---------------------------------------------------------------------------
__global__ void wgen_kernel(const float* __restrict__ routing,
                            const float* __restrict__ ew,
                            short* __restrict__ wbuf) {
    const int ct = blockIdx.x;
    const int cc = ct / 9, t = ct % 9;
    const int b = blockIdx.y;
    const int tid = threadIdx.x;
    const int mf = tid >> 6, l = tid & 63;
    const int o = mf * 16 + (l & 15);
    const int c0 = cc * 32 + ((l >> 4) << 3);
    const float r0 = routing[b * 4 + 0], r1 = routing[b * 4 + 1];
    const float r2 = routing[b * 4 + 2], r3 = routing[b * 4 + 3];
    const float* e0 = ew + (size_t)o * 1152 + (size_t)c0 * 9 + t;
    short8 v;
#pragma unroll
    for (int j = 0; j < 8; ++j) {
        const float* p = e0 + j * 9;
        float val = r0 * p[0] + r1 * p[EWSZ] + r2 * p[2 * EWSZ] + r3 * p[3 * EWSZ];
        v[j] = f2bf(val);
    }
    *(short8*)(wbuf + ((size_t)(b * 4 + cc) * 36864 + ((size_t)(t * 8 + mf) * 64 + l) * 8)) = v;
}

// ---------------------------------------------------------------------------
// Kernel 4: MFMA conv. Block = (b, 8 rows, 128 o). 8 waves, wave = 128o x 64px
// (one h-row per wave). K = 4 chunks of 32 c  x 9 taps, mfma 16x16x32 bf16.
// LDS: ws_s = pre-packed A-frags (73728 B, staged via global_load_lds);
//      xs_s = [10 rows][66 w][40 c-pad] bf16 (52800 B), c contiguous.
// X is reg-prefetched one chunk ahead to overlap HBM with MFMA.
// ---------------------------------------------------------------------------
__global__ __launch_bounds__(512, 2) void conv_kernel(const float* __restrict__ x,
                                                      const short* __restrict__ wbuf,
                                                      float* __restrict__ out) {
    __shared__ __attribute__((aligned(16))) short ws_s[36864];  // 73728 B
    __shared__ __attribute__((aligned(16))) short xs_s[26400];  // 52800 B

    const int b = blockIdx.x, hb = blockIdx.y;
    const int h0 = hb * 8;
    const int tid = threadIdx.x;
    const int wid = tid >> 6, lane = tid & 63;
    const int ln15 = lane & 15, lg = lane >> 4;

    // zero xs (pads + out-of-bounds rows rely on this), then barrier
    for (int i = tid; i < 13200; i += 512) ((int*)xs_s)[i] = 0;

    f32x4 acc[8][4];
#pragma unroll
    for (int m = 0; m < 8; ++m)
#pragma unroll
        for (int n = 0; n < 4; ++n) acc[m][n] = (f32x4){0.f, 0.f, 0.f, 0.f};

    const float* xb = x + (size_t)b * C_ * PLANE;
    const short* wsrc_b = wbuf + (size_t)b * 4 * 36864;

    // task decomposition for X staging: 2560 b128-writes / 512 thr = 5 iters
    int tw[5], tr[5], tcg[5], trow[5];
#pragma unroll
    for (int it = 0; it < 5; ++it) {
        const int task = it * 512 + tid;
        tw[it] = task & 63;
        const int rc = task >> 6;
        tr[it] = rc % 10;
        tcg[it] = rc / 10;
        trow[it] = h0 - 1 + tr[it];
    }

    float xpre[5][8];
    // prologue: load chunk 0
#pragma unroll
    for (int it = 0; it < 5; ++it) {
        const bool valid = (unsigned)trow[it] < 64u;
        const float* src = xb + (size_t)(tcg[it] * 8) * PLANE + trow[it] * 64 + tw[it];
#pragma unroll
        for (int k = 0; k < 8; ++k)
            xpre[it][k] = valid ? src[(size_t)k * PLANE] : 0.f;
    }

    __syncthreads();   // zero-init visible before real writes

    for (int cc = 0; cc < 4; ++cc) {
        // ---- write X tile (bf16, transposed to c-contiguous) ----
#pragma unroll
        for (int it = 0; it < 5; ++it) {
            short8 v;
#pragma unroll
            for (int k = 0; k < 8; ++k) v[k] = f2bf(xpre[it][k]);
            *(short8*)&xs_s[((tr[it] * 66) + 1 + tw[it]) * 40 + tcg[it] * 8] = v;
        }
        // ---- stage W chunk: async global->LDS, linear frag stream ----
        {
            const char* srcb = (const char*)(wsrc_b + (size_t)cc * 36864);
            char* dstb = (char*)ws_s;
#pragma unroll
            for (int it = 0; it < 9; ++it) {
                const int off = (wid * 9 + it) * 1024 + lane * 16;
                __builtin_amdgcn_global_load_lds(
                    (const __attribute__((address_space(1))) void*)(srcb + off),
                    (__attribute__((address_space(3))) void*)(dstb + off), 16, 0, 0);
            }
        }
        __syncthreads();   // drains vmcnt: ws ready, xs visible

        // ---- prefetch next chunk's X into regs (overlaps with MFMA) ----
        if (cc < 3) {
#pragma unroll
            for (int it = 0; it < 5; ++it) {
                const bool valid = (unsigned)trow[it] < 64u;
                const float* src = xb + (size_t)((cc + 1) * 32 + tcg[it] * 8) * PLANE
                                 + trow[it] * 64 + tw[it];
#pragma unroll
                for (int k = 0; k < 8; ++k)
                    xpre[it][k] = valid ? src[(size_t)k * PLANE] : 0.f;
            }
        }

        // ---- compute: 9 taps x (8 mf x 4 nf) mfma ----
#pragma unroll
        for (int t = 0; t < 9; ++t) {
            const int kh = t / 3, kw = t % 3;
            short8 bfr[4];
#pragma unroll
            for (int nf = 0; nf < 4; ++nf)
                bfr[nf] = *(const short8*)&xs_s[(((wid + kh) * 66) + nf * 16 + ln15 + kw) * 40 + lg * 8];
#pragma unroll
            for (int mf = 0; mf < 8; ++mf) {
                short8 af = *(const short8*)&ws_s[((t * 8 + mf) * 64 + lane) * 8];
#pragma unroll
                for (int nf = 0; nf < 4; ++nf)
                    acc[mf][nf] = __builtin_amdgcn_mfma_f32_16x16x32_bf16(
                        af, bfr[nf], acc[mf][nf], 0, 0, 0);
            }
        }
        __syncthreads();
    }

    // ---- epilogue: C/D layout col = lane&15 (px), row = (lane>>4)*4+q (o) ----
    float* ob = out + (size_t)b * OUT_ * PLANE;
    const int h = h0 + wid;
#pragma unroll
    for (int mf = 0; mf < 8; ++mf) {
#pragma unroll
        for (int nf = 0; nf < 4; ++nf) {
            const int w = nf * 16 + ln15;
            const int o0 = mf * 16 + lg * 4;
#pragma unroll
            for (int q = 0; q < 4; ++q)
                ob[((size_t)(o0 + q) * 64 + h) * 64 + w] = acc[mf][nf][q];
        }
    }
}

// ---------------------------------------------------------------------------
extern "C" void kernel_launch(void* const* d_in, const int* in_sizes, int n_in,
                              void* d_out, int out_size, void* d_ws, size_t ws_size,
                              hipStream_t stream) {
    const float* x  = (const float*)d_in[0];   // [32,128,64,64]
    const float* rw = (const float*)d_in[1];   // [256,128]
    const float* rb = (const float*)d_in[2];   // [256]
    const float* ew = (const float*)d_in[3];   // [4,147456]
    float* out = (float*)d_out;                // [32,128,64,64]

    float* pooled  = (float*)d_ws;             // 4096 floats
    float* routing = pooled + 4096;            // 128 floats
    short* wbuf    = (short*)(pooled + 8192);  // 4718592 bf16 (9.4 MB)

    pool_kernel<<<dim3(B_ * C_), 256, 0, stream>>>(x, pooled);
    routing_kernel<<<dim3(B_), 256, 0, stream>>>(pooled, rw, rb, routing);
    wgen_kernel<<<dim3(36, B_), 512, 0, stream>>>(routing, ew, wbuf);
    // grid x = b so XCD = b%8: all h-blocks of a sample share an XCD/L2
    conv_kernel<<<dim3(B_, 8), 512, 0, stream>>>(x, wbuf, out);
}